// Round 1
// baseline (19.394 us; speedup 1.0000x reference)
//
#include <hip/hip_runtime.h>
#include <math.h>

// Problem constants (match reference file).
#define CC 2048   // clusters
#define PP 128    // max points per cluster
#define EE 2048   // edges

__global__ __launch_bounds__(256) void clust_geo_edge_kernel(
    const float* __restrict__ data,        // (N, 8) fp32
    const int*   __restrict__ clusts,      // (C, P)
    const int*   __restrict__ clust_sizes, // (C,)
    const int*   __restrict__ edge_index,  // (2, E)
    float*       __restrict__ out)         // (E, 19) fp32
{
    __shared__ float4 s1[PP];   // x,y,z,|x|^2 for src cluster
    __shared__ float4 s2[PP];   // same for dst cluster
    __shared__ float  red_v[4];
    __shared__ int    red_i[4];

    const int e = blockIdx.x;
    const int t = threadIdx.x;

    const int src = edge_index[e];
    const int dst = edge_index[EE + e];
    const int n1  = clust_sizes[src];
    const int n2  = clust_sizes[dst];

    // ---- stage coords + squared norms into LDS (one point per thread) ----
    {
        const int which = t >> 7;       // 0 -> src/s1, 1 -> dst/s2
        const int p = t & (PP - 1);
        const int c = which ? dst : src;
        const int pt = clusts[c * PP + p];
        // data row is 8 floats, 32B-aligned; cols 1..3 live in the first float4
        float4 v = *reinterpret_cast<const float4*>(data + (size_t)pt * 8);
        const float x = v.y, y = v.z, z = v.w;
        // numpy order: ((x*x + y*y) + z*z), no FMA contraction
        const float sq = __fadd_rn(__fadd_rn(__fmul_rn(x, x), __fmul_rn(y, y)),
                                   __fmul_rn(z, z));
        float4 o; o.x = x; o.y = y; o.z = z; o.w = sq;
        (which ? s2 : s1)[p] = o;
    }
    __syncthreads();

    // ---- all-pairs d2 with argmin (first-occurrence tie-break) ----
    // thread t owns p = t>>1, q in [(t&1)*64, +64)
    const int p   = t >> 1;
    const int qlo = (t & 1) * 64;

    float best_v = INFINITY;
    int   best_i = 0x7fffffff;

    if (p < n1) {
        const float4 a = s1[p];
        int qhi = qlo + 64;
        if (qhi > n2) qhi = n2;
        for (int q = qlo; q < qhi; ++q) {
            const float4 b = s2[q];
            // inner = ((ax*bx + ay*by) + az*bz)  — numpy einsum order, rn ops
            const float inner = __fadd_rn(
                __fadd_rn(__fmul_rn(a.x, b.x), __fmul_rn(a.y, b.y)),
                __fmul_rn(a.z, b.z));
            // d2 = (sq1 + sq2) - 2*inner ; clamp at 0
            float d2 = __fsub_rn(__fadd_rn(a.w, b.w), __fmul_rn(2.0f, inner));
            d2 = fmaxf(d2, 0.0f);
            if (d2 < best_v) {            // strict < keeps earliest index
                best_v = d2;
                best_i = p * PP + q;
            }
        }
    }

    // ---- wave (64-lane) lexicographic min-reduce on (val, idx) ----
    #pragma unroll
    for (int off = 32; off > 0; off >>= 1) {
        const float ov = __shfl_down(best_v, off);
        const int   oi = __shfl_down(best_i, off);
        if (ov < best_v || (ov == best_v && oi < best_i)) {
            best_v = ov; best_i = oi;
        }
    }
    const int wave = t >> 6;
    if ((t & 63) == 0) { red_v[wave] = best_v; red_i[wave] = best_i; }
    __syncthreads();

    // ---- thread 0: final reduce across 4 waves + epilogue ----
    if (t == 0) {
        float bv = red_v[0]; int bi = red_i[0];
        #pragma unroll
        for (int w = 1; w < 4; ++w) {
            const float ov = red_v[w]; const int oi = red_i[w];
            if (ov < bv || (ov == bv && oi < bi)) { bv = ov; bi = oi; }
        }
        const int i1 = bi >> 7;
        const int i2 = bi & (PP - 1);
        const float4 a = s1[i1];
        const float4 b = s2[i2];

        const float d0 = __fsub_rn(a.x, b.x);
        const float d1 = __fsub_rn(a.y, b.y);
        const float d2 = __fsub_rn(a.z, b.z);
        const float ss = __fadd_rn(__fadd_rn(__fmul_rn(d0, d0), __fmul_rn(d1, d1)),
                                   __fmul_rn(d2, d2));
        const float lend = __fsqrt_rn(ss);

        float u0 = d0, u1 = d1, u2 = d2;
        if (lend > 0.0f) {
            u0 = __fdiv_rn(d0, lend);
            u1 = __fdiv_rn(d1, lend);
            u2 = __fdiv_rn(d2, lend);
        }

        float* o = out + (size_t)e * 19;
        o[0] = a.x; o[1] = a.y; o[2] = a.z;
        o[3] = b.x; o[4] = b.y; o[5] = b.z;
        o[6] = u0;  o[7] = u1;  o[8] = u2;
        o[9] = lend;
        o[10] = __fmul_rn(u0, u0); o[11] = __fmul_rn(u0, u1); o[12] = __fmul_rn(u0, u2);
        o[13] = __fmul_rn(u1, u0); o[14] = __fmul_rn(u1, u1); o[15] = __fmul_rn(u1, u2);
        o[16] = __fmul_rn(u2, u0); o[17] = __fmul_rn(u2, u1); o[18] = __fmul_rn(u2, u2);
    }
}

extern "C" void kernel_launch(void* const* d_in, const int* in_sizes, int n_in,
                              void* d_out, int out_size, void* d_ws, size_t ws_size,
                              hipStream_t stream) {
    const float* data        = (const float*)d_in[0];
    const int*   clusts      = (const int*)d_in[1];
    const int*   clust_sizes = (const int*)d_in[2];
    const int*   edge_index  = (const int*)d_in[3];
    float*       out         = (float*)d_out;

    clust_geo_edge_kernel<<<EE, 256, 0, stream>>>(data, clusts, clust_sizes,
                                                  edge_index, out);
}